// Round 1
// 28896.417 us; speedup vs baseline: 1.0943x; 1.0943x over previous
//
#include <hip/hip_runtime.h>
#include <hip/hip_bf16.h>

// RateRNN: B=128,T=4096,I=128,H=512; h'=0.8h+0.2relu(Wi x + Wr h + br); y=wo.h+bo
#define B_ 128
#define T_ 4096
#define I_ 128
#define H_ 512

typedef __attribute__((ext_vector_type(8))) short short8;
typedef __attribute__((ext_vector_type(4))) float f32x4;
typedef __attribute__((ext_vector_type(4))) unsigned short us4;

__device__ __forceinline__ unsigned short f2bf(float f) {
  union { float f; unsigned int u; } v; v.f = f;
  unsigned int r = v.u + 0x7FFFu + ((v.u >> 16) & 1u);  // RNE
  return (unsigned short)(r >> 16);
}

__device__ __forceinline__ short8 cvt8(f32x4 a, f32x4 b) {
  union { short8 s; unsigned short u[8]; } r;
#pragma unroll
  for (int j = 0; j < 4; ++j) { r.u[j] = f2bf(a[j]); r.u[4 + j] = f2bf(b[j]); }
  return r.s;
}

// ---- L3(MALL)-coherent, fence-free exchange primitives ----
// RELAXED+AGENT atomics get sc0/sc1 (bypass L1+L2, coherent at the MALL across
// XCDs) but emit NO buffer_wbl2/buffer_inv fences — unlike ACQ/REL which walk
// the whole L2 every step (that was ~7.5 of the 8.1 us/step).
__device__ __forceinline__ short8 ld_h16(const unsigned short* p) {
  union { short8 s; unsigned long long u[2]; } r;
  r.u[0] = __hip_atomic_load((const unsigned long long*)p,
                             __ATOMIC_RELAXED, __HIP_MEMORY_SCOPE_AGENT);
  r.u[1] = __hip_atomic_load((const unsigned long long*)(p + 4),
                             __ATOMIC_RELAXED, __HIP_MEMORY_SCOPE_AGENT);
  return r.s;
}
__device__ __forceinline__ void st_h8(unsigned short* p, us4 v) {
  union { us4 v; unsigned long long u; } r; r.v = v;
  __hip_atomic_store((unsigned long long*)p, r.u,
                     __ATOMIC_RELAXED, __HIP_MEMORY_SCOPE_AGENT);
}

// ---- workspace layout (bytes) ----
#define WBF_BYTES ((size_t)(H_ * H_ + H_ * I_) * 2)            // 655360
#define CNT_OFF   WBF_BYTES                                    // 8 x u32
#define HX_OFF    (CNT_OFF + 32)                               // 655392 (16B aligned)
#define HX_BYTES  ((size_t)8 * 2 * 16 * H_ * 2)                // 262144
#define YP_OFF    (((HX_OFF + HX_BYTES) + 63) & ~(size_t)63)   // 917568
#define YP_BYTES  ((size_t)8 * T_ * 8 * 16 * 4)                // 16777216
#define WS_NEED   (YP_OFF + YP_BYTES)

// One-time fp32 -> bf16 conversion of w_rec, w_in; also zeroes pair counters.
__global__ void cvt_w_kernel(const float* __restrict__ w_rec,
                             const float* __restrict__ w_in,
                             unsigned short* __restrict__ wbf,
                             unsigned int* __restrict__ cnt) {
  int i = blockIdx.x * blockDim.x + threadIdx.x;
  if (i < H_ * H_) wbf[i] = f2bf(w_rec[i]);
  if (i < H_ * I_) wbf[H_ * H_ + i] = f2bf(w_in[i]);
  if (cnt != nullptr && i < 8)
    __hip_atomic_store(&cnt[i], 0u, __ATOMIC_RELAXED, __HIP_MEMORY_SCOPE_AGENT);
}

// ---------------------------------------------------------------------------
// Pair kernel: 16 blocks x 256 threads (4 waves, 1 wave/SIMD so ~470 VGPRs ok).
// pair = blockIdx%8 owns batch rows pair*16..+15; half = blockIdx/8 owns cols
// half*256..+255; wave owns 64 cols (n0). Weights register-resident (320 VGPR).
// Operand-swapped MFMA: A = weight tile (m=g), B = h^T (n=batch).
//   A[m=lane&15][k=q*8+j], B[k=q*8+j][n=lane&15], C row=q*4+r (g), col=c (batch).
// Cross-block h exchange via MALL: relaxed-agent sc1 stores/loads, manual
// s_waitcnt vmcnt(0) store->counter ordering, relaxed-agent counter — NO
// acquire/release fences (no per-step L2 writeback/invalidate).
// Per-step schedule: [x cvt + W_in MFMAs] (h-independent, overlaps partner) ->
// poll -> h loads + W_rec MFMAs -> epilogue -> publish -> vmcnt(0) -> add ->
// [y-reduce + ypartial + next-x prefetch] (off critical path).
// ---------------------------------------------------------------------------
__global__ __launch_bounds__(256, 1)
void rnn_pair_kernel(const float* __restrict__ inputs,
                     const float* __restrict__ hidden,
                     const float* __restrict__ b_rec,
                     const float* __restrict__ w_out,
                     const unsigned short* __restrict__ wbf,
                     unsigned short* __restrict__ hx,
                     unsigned int* __restrict__ cnt,
                     float* __restrict__ ypartial,
                     float* __restrict__ hfin) {
  const int tid  = threadIdx.x;
  const int wave = tid >> 6;
  const int lane = tid & 63;
  const int q    = lane >> 4;
  const int c    = lane & 15;
  const int pair = blockIdx.x & 7;
  const int half = blockIdx.x >> 3;
  const int wip  = half * 4 + wave;      // wave id within pair (0..7)
  const int r0   = pair * 16;
  const int n0   = half * 256 + wave * 64;

  // ---- weights -> registers (persistent for all 4096 steps) ----
  short8 wr[16][4], wi[4][4];
  {
    const unsigned short* wrp = wbf + (size_t)(n0 + c) * H_ + q * 8;
    const unsigned short* wip_ = wbf + (size_t)H_ * H_ + (size_t)(n0 + c) * I_ + q * 8;
#pragma unroll
    for (int kk = 0; kk < 16; ++kk)
#pragma unroll
      for (int nt = 0; nt < 4; ++nt)
        wr[kk][nt] = *(const short8*)(wrp + (size_t)nt * 16 * H_ + kk * 32);
#pragma unroll
    for (int kk = 0; kk < 4; ++kk)
#pragma unroll
      for (int nt = 0; nt < 4; ++nt)
        wi[kk][nt] = *(const short8*)(wip_ + (size_t)nt * 16 * I_ + kk * 32);
  }

  // Persistent fp32 state in C-layout: hreg[nt][r] = h[b=r0+c][g=n0+nt*16+q*4+r]
  f32x4 hreg[4], brec[4], wout[4];
#pragma unroll
  for (int nt = 0; nt < 4; ++nt)
#pragma unroll
    for (int r = 0; r < 4; ++r) {
      const int g = n0 + nt * 16 + q * 4 + r;
      hreg[nt][r] = hidden[(size_t)(r0 + c) * H_ + g];
      brec[nt][r] = b_rec[g];
      wout[nt][r] = w_out[g];
    }

  unsigned int* mycnt = cnt + pair;
  unsigned short* hx0 = hx + (size_t)(pair * 2) * 16 * H_;  // slot 0
  unsigned short* hx1 = hx0 + 16 * H_;                      // slot 1

  const float* xbase = inputs + (size_t)(r0 + c) * T_ * I_ + q * 8;

  // prefetch x(0)
  f32x4 xn[4][2];
#pragma unroll
  for (int kk = 0; kk < 4; ++kk) {
    xn[kk][0] = *(const f32x4*)(xbase + kk * 32);
    xn[kk][1] = *(const f32x4*)(xbase + kk * 32 + 4);
  }

  // publish phase 0: h(0) -> slot 0 (L3-direct), then counter
#pragma unroll
  for (int nt = 0; nt < 4; ++nt) {
    us4 hb;
#pragma unroll
    for (int r = 0; r < 4; ++r) hb[r] = f2bf(hreg[nt][r]);
    st_h8(hx0 + (size_t)c * H_ + n0 + nt * 16 + q * 4, hb);
  }
  asm volatile("s_waitcnt vmcnt(0)" ::: "memory");
  if (lane == 0)
    __hip_atomic_fetch_add(mycnt, 1u, __ATOMIC_RELAXED, __HIP_MEMORY_SCOPE_AGENT);

  for (int t = 0; t < T_; ++t) {
    // ---- h-independent work first: x(t) convert + W_in projection MFMAs ----
    short8 xc[4];
#pragma unroll
    for (int kk = 0; kk < 4; ++kk) xc[kk] = cvt8(xn[kk][0], xn[kk][1]);
    f32x4 acc[4];
#pragma unroll
    for (int nt = 0; nt < 4; ++nt) acc[nt] = (f32x4){0.f, 0.f, 0.f, 0.f};
#pragma unroll
    for (int kk = 0; kk < 4; ++kk)
#pragma unroll
      for (int nt = 0; nt < 4; ++nt)
        acc[nt] = __builtin_amdgcn_mfma_f32_16x16x32_bf16(wi[kk][nt], xc[kk], acc[nt], 0, 0, 0);

    __builtin_amdgcn_sched_barrier(0);  // keep wi-MFMAs above the poll

    // ---- wait for all 8 waves of the pair to have published phase t ----
    const unsigned target = 8u * (unsigned)(t + 1);
    while (__hip_atomic_load(mycnt, __ATOMIC_RELAXED, __HIP_MEMORY_SCOPE_AGENT) < target) {}
    asm volatile("" ::: "memory");  // keep h loads below the poll

    const unsigned short* hr = ((t & 1) ? hx1 : hx0) + (size_t)c * H_ + q * 8;

    // rec = W_rec(regs) x h^T(L3), 4-deep load pipeline on the B fragments
    short8 hb4[4];
#pragma unroll
    for (int kk = 0; kk < 4; ++kk) hb4[kk] = ld_h16(hr + kk * 32);
#pragma unroll
    for (int kk = 0; kk < 16; ++kk) {
      short8 b = hb4[kk & 3];
      if (kk < 12) hb4[kk & 3] = ld_h16(hr + (kk + 4) * 32);
#pragma unroll
      for (int nt = 0; nt < 4; ++nt)
        acc[nt] = __builtin_amdgcn_mfma_f32_16x16x32_bf16(wr[kk][nt], b, acc[nt], 0, 0, 0);
    }

    // ---- epilogue: relu + leaky update (fp32 master), publish bf16 h ----
    const bool pub = (t + 1 < T_);
    unsigned short* hw = (t & 1) ? hx0 : hx1;  // slot (t+1)&1
    float yl = 0.f;
#pragma unroll
    for (int nt = 0; nt < 4; ++nt) {
      us4 hb;
#pragma unroll
      for (int r = 0; r < 4; ++r) {
        float act = fmaxf(acc[nt][r] + brec[nt][r], 0.f);
        float h = hreg[nt][r] * 0.8f + 0.2f * act;
        hreg[nt][r] = h;
        hb[r] = f2bf(h);
        yl = __builtin_fmaf(wout[nt][r], h, yl);
      }
      if (pub) st_h8(hw + (size_t)c * H_ + n0 + nt * 16 + q * 4, hb);
    }
    if (pub) {
      // release-equivalent for sc1 stores: drain them, then relaxed add.
      asm volatile("s_waitcnt vmcnt(0)" ::: "memory");
      if (lane == 0)
        __hip_atomic_fetch_add(mycnt, 1u, __ATOMIC_RELAXED, __HIP_MEMORY_SCOPE_AGENT);
    }

    // ---- off the partner's critical path: y-reduce, store, next-x prefetch ----
    yl += __shfl_xor(yl, 16, 64);
    yl += __shfl_xor(yl, 32, 64);
    if (q == 0)
      ypartial[(((size_t)pair * T_ + t) * 8 + wip) * 16 + c] = yl;
    {
      const float* xp = xbase + (size_t)((t + 1 < T_) ? (t + 1) : t) * I_;
#pragma unroll
      for (int kk = 0; kk < 4; ++kk) {
        xn[kk][0] = *(const f32x4*)(xp + kk * 32);
        xn[kk][1] = *(const f32x4*)(xp + kk * 32 + 4);
      }
    }
  }

  // h_final (fp32, coalesced dwordx4)
#pragma unroll
  for (int nt = 0; nt < 4; ++nt)
    *(f32x4*)(hfin + (size_t)(r0 + c) * H_ + n0 + nt * 16 + q * 4) = hreg[nt];
}

// Sum the 8 per-wave partials into out[b][t] (+ b_out).
__global__ void reduce_y_kernel(const float* __restrict__ ypartial,
                                const float* __restrict__ b_out,
                                float* __restrict__ out) {
  const int idx = blockIdx.x * 256 + threadIdx.x;  // 524288 = B*T
  const int t = idx & (T_ - 1);
  const int r = idx >> 12;        // batch row 0..127
  const int p = r >> 4, b = r & 15;
  const float* yp = ypartial + (((size_t)p * T_ + t) * 8) * 16 + b;
  float s = b_out[0];
#pragma unroll
  for (int w = 0; w < 8; ++w) s += yp[w * 16];
  out[(size_t)r * T_ + t] = s;
}

// ---------------------------------------------------------------------------
// Fallback (round-1 kernel) for small workspace.
// ---------------------------------------------------------------------------
template <bool WBF16>
__global__ __launch_bounds__(512, 2)
void rnn_kernel_fb(const float* __restrict__ inputs,
                   const float* __restrict__ hidden,
                   const float* __restrict__ w_in_f,
                   const float* __restrict__ w_rec_f,
                   const float* __restrict__ b_rec,
                   const float* __restrict__ w_out,
                   const float* __restrict__ b_out,
                   const unsigned short* __restrict__ wbf,
                   float* __restrict__ out) {
  __shared__ alignas(16) unsigned short hs[2][16][520];
  __shared__ alignas(16) float ypart[2][8][16];

  const int tid  = threadIdx.x;
  const int wave = tid >> 6;
  const int lane = tid & 63;
  const int q    = lane >> 4;
  const int c    = lane & 15;
  const int r0   = blockIdx.x * 16;
  const int n0   = wave * 64;

  for (int e = tid; e < 16 * H_; e += 512) {
    int rr = e >> 9, cc = e & (H_ - 1);
    hs[0][rr][cc] = f2bf(hidden[(size_t)(r0 + rr) * H_ + cc]);
  }

  f32x4 hreg[4];
  float brec[4], wout[4];
#pragma unroll
  for (int nt = 0; nt < 4; ++nt) {
    const int col = n0 + nt * 16 + c;
    brec[nt] = b_rec[col];
    wout[nt] = w_out[col];
#pragma unroll
    for (int r = 0; r < 4; ++r)
      hreg[nt][r] = hidden[(size_t)(r0 + q * 4 + r) * H_ + col];
  }
  const float bout = b_out[0];
  __syncthreads();

  const unsigned short* wrecb = wbf;
  const unsigned short* winb  = wbf + H_ * H_;
  const size_t wr_off = (size_t)(n0 + c) * H_ + q * 8;
  const size_t wi_off = (size_t)(n0 + c) * I_ + q * 8;
  const float* xbase = inputs + (size_t)(r0 + c) * T_ * I_ + q * 8;

#pragma unroll 2
  for (int t = 0; t < T_; ++t) {
    const int rb = t & 1, wb = rb ^ 1;
    f32x4 xf[4][2];
    const float* xp = xbase + (size_t)t * I_;
#pragma unroll
    for (int kk = 0; kk < 4; ++kk) {
      xf[kk][0] = *(const f32x4*)(xp + kk * 32);
      xf[kk][1] = *(const f32x4*)(xp + kk * 32 + 4);
    }
    f32x4 acc[4];
#pragma unroll
    for (int nt = 0; nt < 4; ++nt) acc[nt] = (f32x4){0.f, 0.f, 0.f, 0.f};
    const unsigned short* hrow = &hs[rb][c][q * 8];
#pragma unroll
    for (int kk = 0; kk < 16; ++kk) {
      short8 a = *(const short8*)(hrow + kk * 32);
#pragma unroll
      for (int nt = 0; nt < 4; ++nt) {
        short8 b;
        if constexpr (WBF16) {
          b = *(const short8*)(wrecb + wr_off + (size_t)nt * 16 * H_ + kk * 32);
        } else {
          const float* p = w_rec_f + wr_off + (size_t)nt * 16 * H_ + kk * 32;
          b = cvt8(*(const f32x4*)p, *(const f32x4*)(p + 4));
        }
        acc[nt] = __builtin_amdgcn_mfma_f32_16x16x32_bf16(a, b, acc[nt], 0, 0, 0);
      }
    }
#pragma unroll
    for (int kk = 0; kk < 4; ++kk) {
      short8 ax = cvt8(xf[kk][0], xf[kk][1]);
#pragma unroll
      for (int nt = 0; nt < 4; ++nt) {
        short8 b;
        if constexpr (WBF16) {
          b = *(const short8*)(winb + wi_off + (size_t)nt * 16 * I_ + kk * 32);
        } else {
          const float* p = w_in_f + wi_off + (size_t)nt * 16 * I_ + kk * 32;
          b = cvt8(*(const f32x4*)p, *(const f32x4*)(p + 4));
        }
        acc[nt] = __builtin_amdgcn_mfma_f32_16x16x32_bf16(ax, b, acc[nt], 0, 0, 0);
      }
    }
    float yp2[4] = {0.f, 0.f, 0.f, 0.f};
#pragma unroll
    for (int nt = 0; nt < 4; ++nt) {
#pragma unroll
      for (int r = 0; r < 4; ++r) {
        float act = fmaxf(acc[nt][r] + brec[nt], 0.f);
        float h = hreg[nt][r] * 0.8f + 0.2f * act;
        hreg[nt][r] = h;
        hs[wb][q * 4 + r][n0 + nt * 16 + c] = f2bf(h);
        yp2[r] = __builtin_fmaf(wout[nt], h, yp2[r]);
      }
    }
#pragma unroll
    for (int off = 8; off >= 1; off >>= 1) {
#pragma unroll
      for (int r = 0; r < 4; ++r) yp2[r] += __shfl_xor(yp2[r], off, 64);
    }
    if (c == 0)
      *(f32x4*)&ypart[wb][wave][q * 4] = (f32x4){yp2[0], yp2[1], yp2[2], yp2[3]};
    __syncthreads();
    if (tid < 16) {
      float s = bout;
#pragma unroll
      for (int w = 0; w < 8; ++w) s += ypart[wb][w][tid];
      out[(size_t)(r0 + tid) * T_ + t] = s;
    }
  }
  float* hfin = out + (size_t)B_ * T_;
#pragma unroll
  for (int nt = 0; nt < 4; ++nt)
#pragma unroll
    for (int r = 0; r < 4; ++r)
      hfin[(size_t)(r0 + q * 4 + r) * H_ + n0 + nt * 16 + c] = hreg[nt][r];
}

extern "C" void kernel_launch(void* const* d_in, const int* in_sizes, int n_in,
                              void* d_out, int out_size, void* d_ws, size_t ws_size,
                              hipStream_t stream) {
  const float* inputs = (const float*)d_in[0];
  const float* hidden = (const float*)d_in[1];
  const float* w_in   = (const float*)d_in[2];
  const float* w_rec  = (const float*)d_in[3];
  const float* b_rec  = (const float*)d_in[4];
  const float* w_out  = (const float*)d_in[5];
  const float* b_out  = (const float*)d_in[6];
  float* out = (float*)d_out;

  if (ws_size >= WS_NEED) {
    unsigned short* wbf = (unsigned short*)d_ws;
    unsigned int*   cnt = (unsigned int*)((char*)d_ws + CNT_OFF);
    unsigned short* hx  = (unsigned short*)((char*)d_ws + HX_OFF);
    float*          yp  = (float*)((char*)d_ws + YP_OFF);
    float*          hfin = out + (size_t)B_ * T_;
    cvt_w_kernel<<<dim3((H_ * H_ + 255) / 256), dim3(256), 0, stream>>>(w_rec, w_in, wbf, cnt);
    rnn_pair_kernel<<<dim3(16), dim3(256), 0, stream>>>(
        inputs, hidden, b_rec, w_out, wbf, hx, cnt, yp, hfin);
    reduce_y_kernel<<<dim3((B_ * T_) / 256), dim3(256), 0, stream>>>(yp, b_out, out);
  } else if (ws_size >= WBF_BYTES) {
    unsigned short* wbf = (unsigned short*)d_ws;
    cvt_w_kernel<<<dim3((H_ * H_ + 255) / 256), dim3(256), 0, stream>>>(w_rec, w_in, wbf, nullptr);
    rnn_kernel_fb<true><<<dim3(8), dim3(512), 0, stream>>>(
        inputs, hidden, w_in, w_rec, b_rec, w_out, b_out, wbf, out);
  } else {
    rnn_kernel_fb<false><<<dim3(8), dim3(512), 0, stream>>>(
        inputs, hidden, w_in, w_rec, b_rec, w_out, b_out, (const unsigned short*)nullptr, out);
  }
}

// Round 3
// 27740.771 us; speedup vs baseline: 1.1399x; 1.0417x over previous
//
#include <hip/hip_runtime.h>
#include <hip/hip_bf16.h>

// RateRNN: B=128,T=4096,I=128,H=512; h'=0.8h+0.2relu(Wi x + Wr h + br); y=wo.h+bo
#define B_ 128
#define T_ 4096
#define I_ 128
#define H_ 512

typedef __attribute__((ext_vector_type(8))) short short8;
typedef __attribute__((ext_vector_type(4))) float f32x4;
typedef __attribute__((ext_vector_type(4))) unsigned short us4;

__device__ __forceinline__ unsigned short f2bf(float f) {
  union { float f; unsigned int u; } v; v.f = f;
  unsigned int r = v.u + 0x7FFFu + ((v.u >> 16) & 1u);  // RNE
  return (unsigned short)(r >> 16);
}

__device__ __forceinline__ short8 cvt8(f32x4 a, f32x4 b) {
  union { short8 s; unsigned short u[8]; } r;
#pragma unroll
  for (int j = 0; j < 4; ++j) { r.u[j] = f2bf(a[j]); r.u[4 + j] = f2bf(b[j]); }
  return r.s;
}

// ---- L3(MALL)-coherent, fence-free exchange primitives ----
// RELAXED+AGENT atomics get sc0/sc1 (bypass L1+L2, coherent at the MALL across
// XCDs) but emit NO buffer_wbl2/buffer_inv fences.
__device__ __forceinline__ short8 ld_h16(const unsigned short* p) {
  union { short8 s; unsigned long long u[2]; } r;
  r.u[0] = __hip_atomic_load((const unsigned long long*)p,
                             __ATOMIC_RELAXED, __HIP_MEMORY_SCOPE_AGENT);
  r.u[1] = __hip_atomic_load((const unsigned long long*)(p + 4),
                             __ATOMIC_RELAXED, __HIP_MEMORY_SCOPE_AGENT);
  return r.s;
}
__device__ __forceinline__ void st_h8(unsigned short* p, us4 v) {
  union { us4 v; unsigned long long u; } r; r.v = v;
  __hip_atomic_store((unsigned long long*)p, r.u,
                     __ATOMIC_RELAXED, __HIP_MEMORY_SCOPE_AGENT);
}

// ---- workspace layout (bytes) ----
// Counters are padded to 1 KiB each: 8 pair-counters in one cacheline was a
// single hot MALL line hammered by 64 polling waves + 64 RMWs/step.
#define WBF_BYTES  ((size_t)(H_ * H_ + H_ * I_) * 2)            // 655360
#define CNT_OFF    WBF_BYTES
#define CNT_STRIDE 1024                                         // bytes/pair
#define CNT_BYTES  ((size_t)8 * CNT_STRIDE)                     // 8192
#define HX_OFF     (CNT_OFF + CNT_BYTES)                        // 663552
#define HX_BYTES   ((size_t)8 * 2 * 16 * H_ * 2)                // 262144
#define YP_OFF     (((HX_OFF + HX_BYTES) + 63) & ~(size_t)63)   // 925696
#define YP_BYTES   ((size_t)8 * T_ * 8 * 16 * 4)                // 16777216
#define WS_NEED    (YP_OFF + YP_BYTES)

// One-time fp32 -> bf16 conversion of w_rec, w_in; also zeroes pair counters.
__global__ void cvt_w_kernel(const float* __restrict__ w_rec,
                             const float* __restrict__ w_in,
                             unsigned short* __restrict__ wbf,
                             unsigned int* __restrict__ cnt) {
  int i = blockIdx.x * blockDim.x + threadIdx.x;
  if (i < H_ * H_) wbf[i] = f2bf(w_rec[i]);
  if (i < H_ * I_) wbf[H_ * H_ + i] = f2bf(w_in[i]);
  if (cnt != nullptr && i < 8)
    __hip_atomic_store(&cnt[(size_t)i * (CNT_STRIDE / 4)], 0u,
                       __ATOMIC_RELAXED, __HIP_MEMORY_SCOPE_AGENT);
}

// ---------------------------------------------------------------------------
// Pair kernel: 16 blocks x 256 threads (4 waves, 1 wave/SIMD).
// pair = blockIdx%8 owns batch rows pair*16..+15; half = blockIdx/8 owns cols
// half*256..+255; wave owns 64 cols (n0). Weights register-resident.
// Operand-swapped MFMA: A = weight tile (m=g), B = h^T (n=batch).
// Cross-block h exchange via MALL: relaxed-agent sc1 stores/loads; ordering
// store->counter via counted s_waitcnt (gfx9 vmcnt counts stores too and
// retires in program order: 4 stores then 8 x-loads => vmcnt(8) proves the
// stores completed without draining the loads).
// Per-pair counter padded to 1 KiB (no false sharing across pairs).
// W_rec B-fragment load pipeline deepened to 8 (was latency-chained at 4).
// ---------------------------------------------------------------------------
__global__ __launch_bounds__(256, 1)
void rnn_pair_kernel(const float* __restrict__ inputs,
                     const float* __restrict__ hidden,
                     const float* __restrict__ b_rec,
                     const float* __restrict__ w_out,
                     const unsigned short* __restrict__ wbf,
                     unsigned short* __restrict__ hx,
                     unsigned int* __restrict__ cnt,
                     float* __restrict__ ypartial,
                     float* __restrict__ hfin) {
  const int tid  = threadIdx.x;
  const int wave = tid >> 6;
  const int lane = tid & 63;
  const int q    = lane >> 4;
  const int c    = lane & 15;
  const int pair = blockIdx.x & 7;
  const int half = blockIdx.x >> 3;
  const int wip  = half * 4 + wave;      // wave id within pair (0..7)
  const int r0   = pair * 16;
  const int n0   = half * 256 + wave * 64;

  // ---- weights -> registers (persistent for all 4096 steps) ----
  short8 wr[16][4], wi[4][4];
  {
    const unsigned short* wrp = wbf + (size_t)(n0 + c) * H_ + q * 8;
    const unsigned short* wip_ = wbf + (size_t)H_ * H_ + (size_t)(n0 + c) * I_ + q * 8;
#pragma unroll
    for (int kk = 0; kk < 16; ++kk)
#pragma unroll
      for (int nt = 0; nt < 4; ++nt)
        wr[kk][nt] = *(const short8*)(wrp + (size_t)nt * 16 * H_ + kk * 32);
#pragma unroll
    for (int kk = 0; kk < 4; ++kk)
#pragma unroll
      for (int nt = 0; nt < 4; ++nt)
        wi[kk][nt] = *(const short8*)(wip_ + (size_t)nt * 16 * I_ + kk * 32);
  }

  // Persistent fp32 state in C-layout: hreg[nt][r] = h[b=r0+c][g=n0+nt*16+q*4+r]
  f32x4 hreg[4], brec[4], wout[4];
#pragma unroll
  for (int nt = 0; nt < 4; ++nt)
#pragma unroll
    for (int r = 0; r < 4; ++r) {
      const int g = n0 + nt * 16 + q * 4 + r;
      hreg[nt][r] = hidden[(size_t)(r0 + c) * H_ + g];
      brec[nt][r] = b_rec[g];
      wout[nt][r] = w_out[g];
    }

  unsigned int* mycnt = (unsigned int*)((char*)cnt + (size_t)pair * CNT_STRIDE);
  unsigned short* hx0 = hx + (size_t)(pair * 2) * 16 * H_;  // slot 0
  unsigned short* hx1 = hx0 + 16 * H_;                      // slot 1

  const float* xbase = inputs + (size_t)(r0 + c) * T_ * I_ + q * 8;

  // prefetch x(0)
  f32x4 xn[4][2];
#pragma unroll
  for (int kk = 0; kk < 4; ++kk) {
    xn[kk][0] = *(const f32x4*)(xbase + kk * 32);
    xn[kk][1] = *(const f32x4*)(xbase + kk * 32 + 4);
  }

  // publish phase 0: h(0) -> slot 0 (L3-direct), then counter
#pragma unroll
  for (int nt = 0; nt < 4; ++nt) {
    us4 hb;
#pragma unroll
    for (int r = 0; r < 4; ++r) hb[r] = f2bf(hreg[nt][r]);
    st_h8(hx0 + (size_t)c * H_ + n0 + nt * 16 + q * 4, hb);
  }
  asm volatile("s_waitcnt vmcnt(0)" ::: "memory");
  if (lane == 0)
    __hip_atomic_fetch_add(mycnt, 1u, __ATOMIC_RELAXED, __HIP_MEMORY_SCOPE_AGENT);

  for (int t = 0; t < T_; ++t) {
    // ---- h-independent work first: x(t) convert + W_in projection MFMAs ----
    short8 xc[4];
#pragma unroll
    for (int kk = 0; kk < 4; ++kk) xc[kk] = cvt8(xn[kk][0], xn[kk][1]);
    f32x4 acc[4];
#pragma unroll
    for (int nt = 0; nt < 4; ++nt) acc[nt] = (f32x4){0.f, 0.f, 0.f, 0.f};
#pragma unroll
    for (int kk = 0; kk < 4; ++kk)
#pragma unroll
      for (int nt = 0; nt < 4; ++nt)
        acc[nt] = __builtin_amdgcn_mfma_f32_16x16x32_bf16(wi[kk][nt], xc[kk], acc[nt], 0, 0, 0);

    __builtin_amdgcn_sched_barrier(0);  // keep wi-MFMAs above the poll

    // ---- wait for all 8 waves of the pair to have published phase t ----
    const unsigned target = 8u * (unsigned)(t + 1);
    while (__hip_atomic_load(mycnt, __ATOMIC_RELAXED, __HIP_MEMORY_SCOPE_AGENT) < target) {}
    asm volatile("" ::: "memory");  // keep h loads below the poll

    const unsigned short* hr = ((t & 1) ? hx1 : hx0) + (size_t)c * H_ + q * 8;

    // rec = W_rec(regs) x h^T(L3), 8-deep load pipeline on the B fragments
    short8 hb8[8];
#pragma unroll
    for (int kk = 0; kk < 8; ++kk) hb8[kk] = ld_h16(hr + kk * 32);
#pragma unroll
    for (int kk = 0; kk < 16; ++kk) {
      short8 b = hb8[kk & 7];
      if (kk < 8) hb8[kk & 7] = ld_h16(hr + (kk + 8) * 32);
#pragma unroll
      for (int nt = 0; nt < 4; ++nt)
        acc[nt] = __builtin_amdgcn_mfma_f32_16x16x32_bf16(wr[kk][nt], b, acc[nt], 0, 0, 0);
    }

    // ---- epilogue: relu + leaky update (fp32 master), publish bf16 h ----
    const bool pub = (t + 1 < T_);
    unsigned short* hw = (t & 1) ? hx0 : hx1;  // slot (t+1)&1
    float yl = 0.f;
#pragma unroll
    for (int nt = 0; nt < 4; ++nt) {
      us4 hb;
#pragma unroll
      for (int r = 0; r < 4; ++r) {
        float act = fmaxf(acc[nt][r] + brec[nt][r], 0.f);
        float h = hreg[nt][r] * 0.8f + 0.2f * act;
        hreg[nt][r] = h;
        hb[r] = f2bf(h);
        yl = __builtin_fmaf(wout[nt][r], h, yl);
      }
      if (pub) st_h8(hw + (size_t)c * H_ + n0 + nt * 16 + q * 4, hb);
    }

    // issue next-x prefetch AFTER the publish stores (order pinned): the
    // counted vmcnt(8) below then proves exactly the 4 stores completed
    // (in-order vmcnt retirement) without draining the 8 x-loads.
    __builtin_amdgcn_sched_barrier(0);
    {
      const float* xp = xbase + (size_t)((t + 1 < T_) ? (t + 1) : t) * I_;
#pragma unroll
      for (int kk = 0; kk < 4; ++kk) {
        xn[kk][0] = *(const f32x4*)(xp + kk * 32);
        xn[kk][1] = *(const f32x4*)(xp + kk * 32 + 4);
      }
    }
    __builtin_amdgcn_sched_barrier(0);
    if (pub) {
      asm volatile("s_waitcnt vmcnt(8)" ::: "memory");
      if (lane == 0)
        __hip_atomic_fetch_add(mycnt, 1u, __ATOMIC_RELAXED, __HIP_MEMORY_SCOPE_AGENT);
    }

    // ---- off the partner's critical path: y-reduce + partial store ----
    yl += __shfl_xor(yl, 16, 64);
    yl += __shfl_xor(yl, 32, 64);
    if (q == 0)
      ypartial[(((size_t)pair * T_ + t) * 8 + wip) * 16 + c] = yl;
  }

  // h_final (fp32, coalesced dwordx4)
#pragma unroll
  for (int nt = 0; nt < 4; ++nt)
    *(f32x4*)(hfin + (size_t)(r0 + c) * H_ + n0 + nt * 16 + q * 4) = hreg[nt];
}

// Sum the 8 per-wave partials into out[b][t] (+ b_out).
__global__ void reduce_y_kernel(const float* __restrict__ ypartial,
                                const float* __restrict__ b_out,
                                float* __restrict__ out) {
  const int idx = blockIdx.x * 256 + threadIdx.x;  // 524288 = B*T
  const int t = idx & (T_ - 1);
  const int r = idx >> 12;        // batch row 0..127
  const int p = r >> 4, b = r & 15;
  const float* yp = ypartial + (((size_t)p * T_ + t) * 8) * 16 + b;
  float s = b_out[0];
#pragma unroll
  for (int w = 0; w < 8; ++w) s += yp[w * 16];
  out[(size_t)r * T_ + t] = s;
}

// ---------------------------------------------------------------------------
// Fallback (round-1 kernel) for small workspace.
// ---------------------------------------------------------------------------
template <bool WBF16>
__global__ __launch_bounds__(512, 2)
void rnn_kernel_fb(const float* __restrict__ inputs,
                   const float* __restrict__ hidden,
                   const float* __restrict__ w_in_f,
                   const float* __restrict__ w_rec_f,
                   const float* __restrict__ b_rec,
                   const float* __restrict__ w_out,
                   const float* __restrict__ b_out,
                   const unsigned short* __restrict__ wbf,
                   float* __restrict__ out) {
  __shared__ alignas(16) unsigned short hs[2][16][520];
  __shared__ alignas(16) float ypart[2][8][16];

  const int tid  = threadIdx.x;
  const int wave = tid >> 6;
  const int lane = tid & 63;
  const int q    = lane >> 4;
  const int c    = lane & 15;
  const int r0   = blockIdx.x * 16;
  const int n0   = wave * 64;

  for (int e = tid; e < 16 * H_; e += 512) {
    int rr = e >> 9, cc = e & (H_ - 1);
    hs[0][rr][cc] = f2bf(hidden[(size_t)(r0 + rr) * H_ + cc]);
  }

  f32x4 hreg[4];
  float brec[4], wout[4];
#pragma unroll
  for (int nt = 0; nt < 4; ++nt) {
    const int col = n0 + nt * 16 + c;
    brec[nt] = b_rec[col];
    wout[nt] = w_out[col];
#pragma unroll
    for (int r = 0; r < 4; ++r)
      hreg[nt][r] = hidden[(size_t)(r0 + q * 4 + r) * H_ + col];
  }
  const float bout = b_out[0];
  __syncthreads();

  const unsigned short* wrecb = wbf;
  const unsigned short* winb  = wbf + H_ * H_;
  const size_t wr_off = (size_t)(n0 + c) * H_ + q * 8;
  const size_t wi_off = (size_t)(n0 + c) * I_ + q * 8;
  const float* xbase = inputs + (size_t)(r0 + c) * T_ * I_ + q * 8;

#pragma unroll 2
  for (int t = 0; t < T_; ++t) {
    const int rb = t & 1, wb = rb ^ 1;
    f32x4 xf[4][2];
    const float* xp = xbase + (size_t)t * I_;
#pragma unroll
    for (int kk = 0; kk < 4; ++kk) {
      xf[kk][0] = *(const f32x4*)(xp + kk * 32);
      xf[kk][1] = *(const f32x4*)(xp + kk * 32 + 4);
    }
    f32x4 acc[4];
#pragma unroll
    for (int nt = 0; nt < 4; ++nt) acc[nt] = (f32x4){0.f, 0.f, 0.f, 0.f};
    const unsigned short* hrow = &hs[rb][c][q * 8];
#pragma unroll
    for (int kk = 0; kk < 16; ++kk) {
      short8 a = *(const short8*)(hrow + kk * 32);
#pragma unroll
      for (int nt = 0; nt < 4; ++nt) {
        short8 b;
        if constexpr (WBF16) {
          b = *(const short8*)(wrecb + wr_off + (size_t)nt * 16 * H_ + kk * 32);
        } else {
          const float* p = w_rec_f + wr_off + (size_t)nt * 16 * H_ + kk * 32;
          b = cvt8(*(const f32x4*)p, *(const f32x4*)(p + 4));
        }
        acc[nt] = __builtin_amdgcn_mfma_f32_16x16x32_bf16(a, b, acc[nt], 0, 0, 0);
      }
    }
#pragma unroll
    for (int kk = 0; kk < 4; ++kk) {
      short8 ax = cvt8(xf[kk][0], xf[kk][1]);
#pragma unroll
      for (int nt = 0; nt < 4; ++nt) {
        short8 b;
        if constexpr (WBF16) {
          b = *(const short8*)(winb + wi_off + (size_t)nt * 16 * I_ + kk * 32);
        } else {
          const float* p = w_in_f + wi_off + (size_t)nt * 16 * I_ + kk * 32;
          b = cvt8(*(const f32x4*)p, *(const f32x4*)(p + 4));
        }
        acc[nt] = __builtin_amdgcn_mfma_f32_16x16x32_bf16(ax, b, acc[nt], 0, 0, 0);
      }
    }
    float yp2[4] = {0.f, 0.f, 0.f, 0.f};
#pragma unroll
    for (int nt = 0; nt < 4; ++nt) {
#pragma unroll
      for (int r = 0; r < 4; ++r) {
        float act = fmaxf(acc[nt][r] + brec[nt], 0.f);
        float h = hreg[nt][r] * 0.8f + 0.2f * act;
        hreg[nt][r] = h;
        hs[wb][q * 4 + r][n0 + nt * 16 + c] = f2bf(h);
        yp2[r] = __builtin_fmaf(wout[nt], h, yp2[r]);
      }
    }
#pragma unroll
    for (int off = 8; off >= 1; off >>= 1) {
#pragma unroll
      for (int r = 0; r < 4; ++r) yp2[r] += __shfl_xor(yp2[r], off, 64);
    }
    if (c == 0)
      *(f32x4*)&ypart[wb][wave][q * 4] = (f32x4){yp2[0], yp2[1], yp2[2], yp2[3]};
    __syncthreads();
    if (tid < 16) {
      float s = bout;
#pragma unroll
      for (int w = 0; w < 8; ++w) s += ypart[wb][w][tid];
      out[(size_t)(r0 + tid) * T_ + t] = s;
    }
  }
  float* hfin = out + (size_t)B_ * T_;
#pragma unroll
  for (int nt = 0; nt < 4; ++nt)
#pragma unroll
    for (int r = 0; r < 4; ++r)
      hfin[(size_t)(r0 + q * 4 + r) * H_ + n0 + nt * 16 + c] = hreg[nt][r];
}

extern "C" void kernel_launch(void* const* d_in, const int* in_sizes, int n_in,
                              void* d_out, int out_size, void* d_ws, size_t ws_size,
                              hipStream_t stream) {
  const float* inputs = (const float*)d_in[0];
  const float* hidden = (const float*)d_in[1];
  const float* w_in   = (const float*)d_in[2];
  const float* w_rec  = (const float*)d_in[3];
  const float* b_rec  = (const float*)d_in[4];
  const float* w_out  = (const float*)d_in[5];
  const float* b_out  = (const float*)d_in[6];
  float* out = (float*)d_out;

  if (ws_size >= WS_NEED) {
    unsigned short* wbf = (unsigned short*)d_ws;
    unsigned int*   cnt = (unsigned int*)((char*)d_ws + CNT_OFF);
    unsigned short* hx  = (unsigned short*)((char*)d_ws + HX_OFF);
    float*          yp  = (float*)((char*)d_ws + YP_OFF);
    float*          hfin = out + (size_t)B_ * T_;
    cvt_w_kernel<<<dim3((H_ * H_ + 255) / 256), dim3(256), 0, stream>>>(w_rec, w_in, wbf, cnt);
    rnn_pair_kernel<<<dim3(16), dim3(256), 0, stream>>>(
        inputs, hidden, b_rec, w_out, wbf, hx, cnt, yp, hfin);
    reduce_y_kernel<<<dim3((B_ * T_) / 256), dim3(256), 0, stream>>>(yp, b_out, out);
  } else if (ws_size >= WBF_BYTES) {
    unsigned short* wbf = (unsigned short*)d_ws;
    cvt_w_kernel<<<dim3((H_ * H_ + 255) / 256), dim3(256), 0, stream>>>(w_rec, w_in, wbf, nullptr);
    rnn_kernel_fb<true><<<dim3(8), dim3(512), 0, stream>>>(
        inputs, hidden, w_in, w_rec, b_rec, w_out, b_out, wbf, out);
  } else {
    rnn_kernel_fb<false><<<dim3(8), dim3(512), 0, stream>>>(
        inputs, hidden, w_in, w_rec, b_rec, w_out, b_out, (const unsigned short*)nullptr, out);
  }
}